// Round 6
// baseline (1376.803 us; speedup 1.0000x reference)
//
#include <hip/hip_runtime.h>
#include <hip/hip_bf16.h>
#include <cstdint>

// Neural ODE: 10 Heun steps of f(y) = tanh(y@W1 + b1)@W2 + b2
// BATCH=8192, D=512, H=2048, dt=0.1
// R12: producer/consumer wave specialization on the proven CW=256 geometry.
// Waves 0-7 = producers (GEMM1: W1 L2-stream + yA LDS + tanh/scatter).
// Waves 8-15 = consumers (GEMM2: W2 L2-stream + hA LDS -> accY).
// 9 windows, 1 barrier each; producer writes hA[t&1] while consumer reads
// hA[(t-1)&1]. The two L2 weight streams + two LDS streams + VALU + MFMA
// now overlap ACROSS waves by construction (2 prod + 2 cons waves / SIMD),
// instead of relying on the scheduler to overlap a serial per-wave chain
// (R11 showed the compiler folds register prefetch away; VGPR 56->48).
// Model: LDS 74K cyc + L2 75K cyc per CU/eval were summing (160K measured).
// If they overlap: wall -> ~80-110K cyc = 42-55us/eval.
// Dead axes: R7 reg-resident A (remats), R8/R10 CW=512 (regressed),
// R11 rotating reg prefetch (compiler folds it).

#define BATCHN 8192
#define DDIM 512
#define HDIM 2048
#define CW 256          // chunk width over H
#define NCH (HDIM / CW) // 8

typedef short short8 __attribute__((ext_vector_type(8)));
typedef float floatx4 __attribute__((ext_vector_type(4)));

__device__ __forceinline__ unsigned short f2bf(float f) {
  union { __hip_bfloat16 h; unsigned short u; } cv;
  cv.h = __float2bfloat16(f);
  return cv.u;
}

__device__ __forceinline__ float fast_tanh(float x) {
  float e = __expf(2.0f * x);
  return 1.0f - 2.0f / (e + 1.0f);
}

__device__ __forceinline__ void glds16(const void* g, void* l) {
  __builtin_amdgcn_global_load_lds(
      (const __attribute__((address_space(1))) void*)(uintptr_t)g,
      (__attribute__((address_space(3))) void*)(uint32_t)(uintptr_t)l,
      16, 0, 0);
}

// Fragment conventions (verified by R1-R11 passing kernels):
//  A-frag (16x16x32): lane holds A[m = l15][k = quad*8 + j], j=0..7 (16B)
//  B-frag:            lane holds B[n = l15][k = quad*8 + j]  (BT row-major)
//  C/D:               row = quad*4 + r, col = l15
// Packed buffers: frag f stored at [(f*64 + lane)*8] halves.
//  yPack: f = rb*16 + ks   (rb = batch-row/16: 0..511, ks = D k-step: 0..15)
//  w1p:   f = nb*16 + kb   (nb = H col-tile: 0..127,   kb = D k-step: 0..15)
//  w2p:   f = nb*64 + kb   (nb = D col-tile: 0..31,    kb = H k-step: 0..63)

__global__ __launch_bounds__(1024, 4) void fused_feval(
    const unsigned short* __restrict__ yPack,   // packed bf16 eval input
    const unsigned short* __restrict__ w1p,
    const unsigned short* __restrict__ w2p,
    const float* __restrict__ b1,
    const float* __restrict__ b2,
    const float* __restrict__ stateIn,   // EPI1: y fp32 ; EPI2: p fp32
    float* __restrict__ stateOut,        // EPI1: p      ; EPI2: ynew
    unsigned short* __restrict__ outPack,// packed bf16 next-eval input
    int epi) {                           // 1 or 2
  __shared__ unsigned short yA[32 * 512];       // 32 KB, frag (mt*16+ks)
  __shared__ unsigned short hA[2][32 * CW];     // 2 x 16 KB, frag (mt*8+ks)

  const int tid  = threadIdx.x;
  const int lane = tid & 63;
  const int w    = tid >> 6;    // wave 0..15
  const int wc   = w & 7;       // role-local wave id 0..7
  const bool prod = (w < 8);
  const int quad = lane >> 4;
  const int l15  = lane & 15;
  const int blk  = blockIdx.x;  // 0..255
  const int B0   = blk * 32;    // slab base row

  // phase0: linear copy of this block's 32 KB packed y-slab into LDS.
  {
    const unsigned short* src = yPack + (size_t)blk * (32 * 512);
    glds16(src + (size_t)tid * 8, &yA[tid * 8]);
    glds16(src + (size_t)(1024 + tid) * 8, &yA[(1024 + tid) * 8]);
  }
  __syncthreads();

  floatx4 accY[2][4] = {};  // consumers: [mt][i], cols wc*64 + i*16 + l15

  // 9 windows: producers do chunk t (t<8); consumers do chunk t-1 (t>=1).
  for (int t = 0; t < NCH + 1; ++t) {
    if (prod) {
      if (t < NCH) {
        // ---- GEMM1: h[:, t*256 + (wc*2+{0,1})*16] = tanh(y@W1 + b1) ----
        floatx4 acc1[2][2] = {};  // [i1][mt]
        const unsigned short* w1b =
            w1p + ((size_t)((t * 16 + wc * 2) * 16) * 64 + lane) * 8;
        const float bb0 = b1[t * CW + (wc * 2 + 0) * 16 + l15];
        const float bb1f = b1[t * CW + (wc * 2 + 1) * 16 + l15];
#pragma unroll
        for (int ks = 0; ks < 16; ++ks) {
          short8 a0  = *(const short8*)&yA[((0 * 16 + ks) * 64 + lane) * 8];
          short8 a1  = *(const short8*)&yA[((1 * 16 + ks) * 64 + lane) * 8];
          short8 b0  = *(const short8*)(w1b + (size_t)ks * 512);
          short8 b1v = *(const short8*)(w1b + (size_t)(16 + ks) * 512);
          acc1[0][0] = __builtin_amdgcn_mfma_f32_16x16x32_bf16(a0, b0, acc1[0][0], 0, 0, 0);
          acc1[0][1] = __builtin_amdgcn_mfma_f32_16x16x32_bf16(a1, b0, acc1[0][1], 0, 0, 0);
          acc1[1][0] = __builtin_amdgcn_mfma_f32_16x16x32_bf16(a0, b1v, acc1[1][0], 0, 0, 0);
          acc1[1][1] = __builtin_amdgcn_mfma_f32_16x16x32_bf16(a1, b1v, acc1[1][1], 0, 0, 0);
        }
        // bias + tanh + scatter into hA[t&1] (A-frag layout, k = h-col)
        unsigned short* hbuf = hA[t & 1];
#pragma unroll
        for (int i1 = 0; i1 < 2; ++i1) {
          const int kloc = (wc * 2 + i1) * 16 + l15;   // 0..255
          const float bb = i1 ? bb1f : bb0;
          const int ksa = kloc >> 5;
          const int qa  = (kloc & 31) >> 3;
          const int kb7 = kloc & 7;
#pragma unroll
          for (int mt = 0; mt < 2; ++mt)
#pragma unroll
            for (int r = 0; r < 4; ++r) {
              const int m15 = quad * 4 + r;            // C row -> A-frag m
              hbuf[((mt * 8 + ksa) * 64 + qa * 16 + m15) * 8 + kb7] =
                  f2bf(fast_tanh(acc1[i1][mt][r] + bb));
            }
        }
      }
    } else {
      if (t >= 1) {
        // ---- GEMM2: accY += h(t-1) @ W2-slice ----
        const int cc = t - 1;
        const unsigned short* hp = hA[cc & 1];
        // frag f = (wc*4+i)*64 + cc*8 + ks; halves offset (f*64+lane)*8
        const unsigned short* w2b =
            w2p + ((size_t)(wc * 4 * 64 + cc * 8) * 64 + lane) * 8;
#pragma unroll
        for (int ks = 0; ks < 8; ++ks) {
          short8 ha0 = *(const short8*)&hp[((0 * 8 + ks) * 64 + lane) * 8];
          short8 ha1 = *(const short8*)&hp[((1 * 8 + ks) * 64 + lane) * 8];
#pragma unroll
          for (int i = 0; i < 4; ++i) {
            short8 b = *(const short8*)(w2b + (size_t)i * 32768 + (size_t)ks * 512);
            accY[0][i] = __builtin_amdgcn_mfma_f32_16x16x32_bf16(ha0, b, accY[0][i], 0, 0, 0);
            accY[1][i] = __builtin_amdgcn_mfma_f32_16x16x32_bf16(ha1, b, accY[1][i], 0, 0, 0);
          }
        }
      }
    }
    __syncthreads();
  }

  // Epilogue: consumers add b2, Heun-combine with fp32 state, pack bf16.
  unsigned short* pbuf = &hA[0][0];  // 32 KB staging, yPack layout (mt*16+ksa)
  if (!prod) {
#pragma unroll
    for (int i = 0; i < 4; ++i) {
      const int ncol = wc * 64 + i * 16 + l15;  // 0..511
      const float bb = b2[ncol];
      const int ksa = ncol >> 5;
      const int qa  = (ncol & 31) >> 3;
      const int nb7 = ncol & 7;
#pragma unroll
      for (int mt = 0; mt < 2; ++mt)
#pragma unroll
        for (int r = 0; r < 4; ++r) {
          const int row = B0 + mt * 16 + quad * 4 + r;
          const size_t idx = (size_t)row * DDIM + ncol;
          const float v = accY[mt][i][r] + bb;
          float nv;
          if (epi == 1) {
            const float y = stateIn[idx];
            stateOut[idx] = y + 0.05f * v;   // p = y + (dt/2)*k1
            nv = y + 0.1f * v;               // ymid
          } else {
            const float yn = stateIn[idx] + 0.05f * v;  // ynew = p + (dt/2)*k2
            stateOut[idx] = yn;
            nv = yn;
          }
          const int m15 = quad * 4 + r;
          pbuf[((mt * 16 + ksa) * 64 + qa * 16 + m15) * 8 + nb7] = f2bf(nv);
        }
    }
  }
  __syncthreads();
  {
    unsigned short* dst = outPack + (size_t)blk * (32 * 512);
#pragma unroll
    for (int p = 0; p < 2; ++p) {
      short8 v = *(const short8*)&pbuf[(size_t)(p * 1024 + tid) * 8];
      *(short8*)&dst[(size_t)(p * 1024 + tid) * 8] = v;
    }
  }
}

// Pack weight [K][N] fp32 -> B-frag order: frag f = nb*KB + kb,
// lane entry = src[kb*32 + quad*8 + j][nb*16 + l15].
__global__ void pack_b(const float* __restrict__ src, unsigned short* __restrict__ dst,
                       int KB, int N) {
  const int t = blockIdx.x * 256 + threadIdx.x;
  const int lane = t & 63, f = t >> 6;
  const int nb = f / KB, kb = f % KB;
  const int quad = lane >> 4, l15 = lane & 15;
  const int k0 = kb * 32 + quad * 8, n = nb * 16 + l15;
  short8 v;
#pragma unroll
  for (int j = 0; j < 8; ++j)
    v[j] = (short)f2bf(src[(size_t)(k0 + j) * N + n]);
  *(short8*)&dst[(size_t)t * 8] = v;
}

// y0 fp32 [8192][512] -> yF fp32 copy + packed bf16 A-frags.
__global__ void pack_y(const float* __restrict__ y0, float* __restrict__ yF,
                       unsigned short* __restrict__ ypk) {
  const int t = blockIdx.x * 256 + threadIdx.x;
  const int lane = t & 63, f = t >> 6;
  const int rb = f >> 4, ks = f & 15;
  const int quad = lane >> 4, l15 = lane & 15;
  const int row = rb * 16 + l15, c0 = ks * 32 + quad * 8;
  short8 v;
#pragma unroll
  for (int j = 0; j < 8; ++j) {
    const float x = y0[(size_t)row * DDIM + c0 + j];
    yF[(size_t)row * DDIM + c0 + j] = x;
    v[j] = (short)f2bf(x);
  }
  *(short8*)&ypk[(size_t)t * 8] = v;
}

extern "C" void kernel_launch(void* const* d_in, const int* in_sizes, int n_in,
                              void* d_out, int out_size, void* d_ws, size_t ws_size,
                              hipStream_t stream) {
  const float* y0 = (const float*)d_in[0];
  const float* W1 = (const float*)d_in[1];  // [512][2048]
  const float* b1 = (const float*)d_in[2];  // [2048]
  const float* W2 = (const float*)d_in[3];  // [2048][512]
  const float* b2 = (const float*)d_in[4];  // [512]

  char* ws = (char*)d_ws;
  float*          yF   = (float*)(ws);                         // 16 MB
  float*          pF   = (float*)(ws + (size_t)(16u << 20));   // 16 MB
  unsigned short* ypk  = (unsigned short*)(ws + (size_t)(32u << 20)); // 8 MB
  unsigned short* ympk = (unsigned short*)(ws + (size_t)(40u << 20)); // 8 MB
  unsigned short* w1p  = (unsigned short*)(ws + (size_t)(48u << 20)); // 2 MB
  unsigned short* w2p  = (unsigned short*)(ws + (size_t)(50u << 20)); // 2 MB

  // Pre-pass: pack weights (2048 frags each) and y0 (8192 frags).
  pack_b<<<512, 256, 0, stream>>>(W1, w1p, 16, HDIM);
  pack_b<<<512, 256, 0, stream>>>(W2, w2p, 64, DDIM);
  pack_y<<<2048, 256, 0, stream>>>(y0, yF, ypk);

  const dim3 grid(256), blkd(1024);
  for (int s = 0; s < 10; ++s) {
    // eval1: k1 = f(y); p = y + 0.05*k1; ymid = y + 0.1*k1 (packed)
    fused_feval<<<grid, blkd, 0, stream>>>(ypk, w1p, w2p, b1, b2, yF, pF, ympk, 1);
    // eval2: k2 = f(ymid); ynew = p + 0.05*k2 (fp32 + packed)
    float* yOut = (s == 9) ? (float*)d_out : yF;
    fused_feval<<<grid, blkd, 0, stream>>>(ympk, w1p, w2p, b1, b2, pF, yOut, ypk, 2);
  }
}

// Round 7
// 1113.043 us; speedup vs baseline: 1.2370x; 1.2370x over previous
//
#include <hip/hip_runtime.h>
#include <hip/hip_bf16.h>
#include <cstdint>

// Neural ODE: 10 Heun steps of f(y) = tanh(y@W1 + b1)@W2 + b2
// BATCH=8192, D=512, H=2048, dt=0.1
// R13: 32x32x16 MFMA restructure. Same proven schedule as R6/R11 (one
// barrier per chunk, double-buffered hA, phase1(c)+scatter(c)+phase2(c-1)
// in one window), but both GEMMs use mfma_f32_32x32x16_bf16:
//   - 32K FLOP/instr from 2KB operands (2x FLOP per operand byte)
//   - MFMA instrs 8192->4096, ds_read_b128 6144->4096 per CU/eval
//   - vmem bytes unchanged (4MB weights/CU/eval, the irreducible stream)
// Wave tiling: 1 m-tile (32 rows) x 1 n-tile (32 cols) per wave.
// GEMM1: 64 n-tiles over H, CW=512 -> 16/chunk, 1/wave. K=512 -> 32 ks.
// GEMM2: 16 n-tiles over D, 1/wave. K per chunk = 32 ks.
// Layouts: C/D col=lane&31, row=(reg&3)+8*(reg>>2)+4*(lane>>5) [HW-verified
// m74/m101]. A/B: lane holds X[p=lane&31][k=(lane>>5)*8+j] (generalization
// of our verified 16x16x32 convention).
// Dead axes: R7 reg-resident A (remats), R8 two-barrier scatter (+29%),
// R10 CW=512@16x16 (regressed), R11 reg prefetch (folded), R12 wave
// specialization (role imbalance).

#define BATCHN 8192
#define DDIM 512
#define HDIM 2048
#define CW 512          // chunk width over H
#define NCH (HDIM / CW) // 4

typedef short short8 __attribute__((ext_vector_type(8)));
typedef float floatx16 __attribute__((ext_vector_type(16)));

__device__ __forceinline__ unsigned short f2bf(float f) {
  union { __hip_bfloat16 h; unsigned short u; } cv;
  cv.h = __float2bfloat16(f);
  return cv.u;
}

__device__ __forceinline__ float fast_tanh(float x) {
  float e = __expf(2.0f * x);
  return 1.0f - 2.0f / (e + 1.0f);
}

__device__ __forceinline__ void glds16(const void* g, void* l) {
  __builtin_amdgcn_global_load_lds(
      (const __attribute__((address_space(1))) void*)(uintptr_t)g,
      (__attribute__((address_space(3))) void*)(uint32_t)(uintptr_t)l,
      16, 0, 0);
}

// 32x32x16 fragment conventions:
//  A-frag: lane holds A[m = lane&31][k = (lane>>5)*8 + j], j=0..7 (16B)
//  B-frag: lane holds B[n = lane&31][k = (lane>>5)*8 + j]   (BT row-major)
//  C/D:    col = lane&31, row = (reg&3) + 8*(reg>>2) + 4*(lane>>5)
// Packed buffers: frag f stored at [(f*64 + lane)*8] halves.
//  yPack: f = rb*32 + ks   (rb = batch-row/32: 0..255, ks = D k-step: 0..31)
//  w1p:   f = nb*32 + kb   (nb = H col-tile/32: 0..63,  kb = D k-step: 0..31)
//  w2p:   f = nb*128 + kb  (nb = D col-tile/32: 0..15,  kb = H k-step: 0..127)

__global__ __launch_bounds__(1024, 4) void fused_feval(
    const unsigned short* __restrict__ yPack,   // packed bf16 eval input
    const unsigned short* __restrict__ w1p,
    const unsigned short* __restrict__ w2p,
    const float* __restrict__ b1,
    const float* __restrict__ b2,
    const float* __restrict__ stateIn,   // EPI1: y fp32 ; EPI2: p fp32
    float* __restrict__ stateOut,        // EPI1: p      ; EPI2: ynew
    unsigned short* __restrict__ outPack,// packed bf16 next-eval input
    int epi) {                           // 1 or 2
  __shared__ unsigned short yA[32 * 512];       // 32 KB, A32 frags ks=0..31
  __shared__ unsigned short hA[2][32 * 512];    // 2 x 32 KB, A32 frags/chunk

  const int tid  = threadIdx.x;
  const int lane = tid & 63;
  const int w    = tid >> 6;    // wave 0..15
  const int c31  = lane & 31;
  const int lhi  = lane >> 5;   // 0..1
  const int blk  = blockIdx.x;  // 0..255
  const int B0   = blk * 32;    // slab base row

  // phase0: linear copy of this block's 32 KB packed y-slab into LDS.
  {
    const unsigned short* src = yPack + (size_t)blk * (32 * 512);
    glds16(src + (size_t)tid * 8, &yA[tid * 8]);
    glds16(src + (size_t)(1024 + tid) * 8, &yA[(1024 + tid) * 8]);
  }

  // preload per-chunk b1 biases: lane's GEMM1 output col in chunk c is
  // (c*16+w)*32 + c31 -> b1[c*CW + w*32 + c31].
  float bb1v[NCH];
#pragma unroll
  for (int c = 0; c < NCH; ++c) bb1v[c] = b1[c * CW + w * 32 + c31];

  __syncthreads();

  floatx16 accY = {};  // GEMM2 acc: col = w*32 + c31, 16 rows

#pragma unroll
  for (int c = 0; c < NCH; ++c) {
    // ---- phase1: acc1 = y @ W1[:, (c*16+w)*32 .. +32] ----
    floatx16 acc1 = {};
    const unsigned short* w1b =
        w1p + ((size_t)((c * 16 + w) * 32) * 64 + lane) * 8;
#pragma unroll
    for (int ks = 0; ks < 32; ++ks) {
      short8 a = *(const short8*)&yA[(ks * 64 + lane) * 8];
      short8 b = *(const short8*)(w1b + (size_t)ks * 512);
      acc1 = __builtin_amdgcn_mfma_f32_32x32x16_bf16(a, b, acc1, 0, 0, 0);
    }

    // bias + tanh + scatter into hA[c&1] (A32-frag layout, k = col in chunk)
    {
      unsigned short* hbuf = hA[c & 1];
      const int kloc = w * 32 + c31;        // this lane's h-col in chunk
      const float bb = bb1v[c];
      const int ksf = kloc >> 4;            // frag 0..31
      const int lh  = (kloc >> 3) & 1;
      const int jj  = kloc & 7;
      const int mhi = lhi * 4;
#pragma unroll
      for (int reg = 0; reg < 16; ++reg) {
        const int m = (reg & 3) + 8 * (reg >> 2) + mhi;   // C/D row
        hbuf[(ksf * 64 + (m + 32 * lh)) * 8 + jj] =
            f2bf(fast_tanh(acc1[reg] + bb));
      }
    }

    // ---- phase2 for chunk c-1: accY += h_prev @ W2-slice ----
    if (c > 0) {
      const int cc = c - 1;
      const unsigned short* hp = hA[cc & 1];
      const unsigned short* w2b =
          w2p + ((size_t)(w * 128 + cc * 32) * 64 + lane) * 8;
#pragma unroll
      for (int ks = 0; ks < 32; ++ks) {
        short8 a = *(const short8*)&hp[(ks * 64 + lane) * 8];
        short8 b = *(const short8*)(w2b + (size_t)ks * 512);
        accY = __builtin_amdgcn_mfma_f32_32x32x16_bf16(a, b, accY, 0, 0, 0);
      }
    }
    __syncthreads();
  }
  // tail phase2: chunk NCH-1 (buffer (NCH-1)&1 = 1)
  {
    const int cc = NCH - 1;
    const unsigned short* hp = hA[cc & 1];
    const unsigned short* w2b =
        w2p + ((size_t)(w * 128 + cc * 32) * 64 + lane) * 8;
#pragma unroll
    for (int ks = 0; ks < 32; ++ks) {
      short8 a = *(const short8*)&hp[(ks * 64 + lane) * 8];
      short8 b = *(const short8*)(w2b + (size_t)ks * 512);
      accY = __builtin_amdgcn_mfma_f32_32x32x16_bf16(a, b, accY, 0, 0, 0);
    }
  }
  __syncthreads();  // all waves done reading hA before reuse as pack staging

  // Epilogue: add b2, Heun combine with fp32 state, pack bf16 result.
  {
    unsigned short* pbuf = &hA[0][0];  // 32 KB staging, yPack A32 layout
    const int ncol = w * 32 + c31;     // 0..511
    const float bb = b2[ncol];
    const int ksf = ncol >> 4;
    const int lh  = (ncol >> 3) & 1;
    const int jj  = ncol & 7;
    const int mhi = lhi * 4;
#pragma unroll
    for (int reg = 0; reg < 16; ++reg) {
      const int mrow = (reg & 3) + 8 * (reg >> 2) + mhi;
      const int row = B0 + mrow;
      const size_t idx = (size_t)row * DDIM + ncol;
      const float v = accY[reg] + bb;
      float nv;
      if (epi == 1) {
        const float y = stateIn[idx];
        stateOut[idx] = y + 0.05f * v;   // p = y + (dt/2)*k1
        nv = y + 0.1f * v;               // ymid
      } else {
        const float yn = stateIn[idx] + 0.05f * v;  // ynew = p + (dt/2)*k2
        stateOut[idx] = yn;
        nv = yn;
      }
      pbuf[(ksf * 64 + (mrow + 32 * lh)) * 8 + jj] = f2bf(nv);
    }
    __syncthreads();
    unsigned short* dst = outPack + (size_t)blk * (32 * 512);
#pragma unroll
    for (int p = 0; p < 2; ++p) {
      short8 v = *(const short8*)&pbuf[(size_t)(p * 1024 + tid) * 8];
      *(short8*)&dst[(size_t)(p * 1024 + tid) * 8] = v;
    }
  }
}

// Pack weight [K][N] fp32 -> 32x32 B-frag order: frag f = nb*KB + kb,
// lane entry = src[kb*16 + (lane>>5)*8 + j][nb*32 + (lane&31)].
__global__ void pack_b(const float* __restrict__ src, unsigned short* __restrict__ dst,
                       int KB, int N) {
  const int t = blockIdx.x * 256 + threadIdx.x;
  const int lane = t & 63, f = t >> 6;
  const int nb = f / KB, kb = f % KB;
  const int k0 = kb * 16 + (lane >> 5) * 8, n = nb * 32 + (lane & 31);
  short8 v;
#pragma unroll
  for (int j = 0; j < 8; ++j)
    v[j] = (short)f2bf(src[(size_t)(k0 + j) * N + n]);
  *(short8*)&dst[(size_t)t * 8] = v;
}

// y0 fp32 [8192][512] -> yF fp32 copy + packed bf16 32x32 A-frags.
// frag f = rb*32 + ks; lane entry = y0[rb*32 + (lane&31)][ks*16 + (lane>>5)*8 + j]
__global__ void pack_y(const float* __restrict__ y0, float* __restrict__ yF,
                       unsigned short* __restrict__ ypk) {
  const int t = blockIdx.x * 256 + threadIdx.x;
  const int lane = t & 63, f = t >> 6;
  const int rb = f >> 5, ks = f & 31;
  const int row = rb * 32 + (lane & 31), c0 = ks * 16 + (lane >> 5) * 8;
  short8 v;
#pragma unroll
  for (int j = 0; j < 8; ++j) {
    const float x = y0[(size_t)row * DDIM + c0 + j];
    yF[(size_t)row * DDIM + c0 + j] = x;
    v[j] = (short)f2bf(x);
  }
  *(short8*)&ypk[(size_t)t * 8] = v;
}

extern "C" void kernel_launch(void* const* d_in, const int* in_sizes, int n_in,
                              void* d_out, int out_size, void* d_ws, size_t ws_size,
                              hipStream_t stream) {
  const float* y0 = (const float*)d_in[0];
  const float* W1 = (const float*)d_in[1];  // [512][2048]
  const float* b1 = (const float*)d_in[2];  // [2048]
  const float* W2 = (const float*)d_in[3];  // [2048][512]
  const float* b2 = (const float*)d_in[4];  // [512]

  char* ws = (char*)d_ws;
  float*          yF   = (float*)(ws);                         // 16 MB
  float*          pF   = (float*)(ws + (size_t)(16u << 20));   // 16 MB
  unsigned short* ypk  = (unsigned short*)(ws + (size_t)(32u << 20)); // 8 MB
  unsigned short* ympk = (unsigned short*)(ws + (size_t)(40u << 20)); // 8 MB
  unsigned short* w1p  = (unsigned short*)(ws + (size_t)(48u << 20)); // 2 MB
  unsigned short* w2p  = (unsigned short*)(ws + (size_t)(50u << 20)); // 2 MB

  // Pre-pass: pack weights (2048 frags each) and y0 (8192 frags).
  pack_b<<<512, 256, 0, stream>>>(W1, w1p, 32, HDIM);
  pack_b<<<512, 256, 0, stream>>>(W2, w2p, 128, DDIM);
  pack_y<<<2048, 256, 0, stream>>>(y0, yF, ypk);

  const dim3 grid(256), blkd(1024);
  for (int s = 0; s < 10; ++s) {
    // eval1: k1 = f(y); p = y + 0.05*k1; ymid = y + 0.1*k1 (packed)
    fused_feval<<<grid, blkd, 0, stream>>>(ypk, w1p, w2p, b1, b2, yF, pF, ympk, 1);
    // eval2: k2 = f(ymid); ynew = p + 0.05*k2 (fp32 + packed)
    float* yOut = (s == 9) ? (float*)d_out : yF;
    fused_feval<<<grid, blkd, 0, stream>>>(ympk, w1p, w2p, b1, b2, pF, yOut, ypk, 2);
  }
}